// Round 3
// baseline (3841.271 us; speedup 1.0000x reference)
//
#include <hip/hip_runtime.h>
#include <math.h>

typedef unsigned short ushort_t;
typedef __attribute__((ext_vector_type(4))) float f32x4;
typedef __attribute__((ext_vector_type(8))) short short8;

constexpr int BATCH = 8, T = 1024, C = 1024, NH = 16, HD = 64, NL = 8;
constexpr int MROWS = BATCH * T;  // 8192
constexpr int CS = 3 * C;         // packed QKV row stride

__device__ __forceinline__ ushort_t f2bf(float f) {
  unsigned u = __builtin_bit_cast(unsigned, f);
  u += 0x7fffu + ((u >> 16) & 1u);
  return (ushort_t)(u >> 16);
}

__device__ __forceinline__ void gload_lds16(const ushort_t* g, ushort_t* l) {
  __builtin_amdgcn_global_load_lds(
      (const __attribute__((address_space(1))) unsigned int*)g,
      (__attribute__((address_space(3))) unsigned int*)l, 16, 0, 0);
}

// ---------------------------------------------------------------------------
// Per-layer weight conversion f32->bf16 + QKV packing (unchanged).
// ---------------------------------------------------------------------------
__global__ __launch_bounds__(256, 8)
void convw_kernel(const float* __restrict__ Wq, const float* __restrict__ Wk,
                  const float* __restrict__ Wv, const float* __restrict__ Wo,
                  const float* __restrict__ W1, const float* __restrict__ W2,
                  const float* __restrict__ bq, const float* __restrict__ bk,
                  const float* __restrict__ bv,
                  ushort_t* __restrict__ wqkv, ushort_t* __restrict__ wo,
                  ushort_t* __restrict__ w1, ushort_t* __restrict__ w2,
                  float* __restrict__ bqkv)
{
  if (blockIdx.x == 6144) {
    int t = threadIdx.x;
    if (t < 384) {
      const float* s = (t < 128) ? (bq + t * 8)
                     : (t < 256) ? (bk + (t - 128) * 8)
                                 : (bv + (t - 256) * 8);
      f32x4 a = ((const f32x4*)s)[0], b = ((const f32x4*)s)[1];
      ((f32x4*)(bqkv + t * 8))[0] = a;
      ((f32x4*)(bqkv + t * 8))[1] = b;
    }
    return;
  }
  int g = blockIdx.x * 256 + threadIdx.x;
  const float* src;
  ushort_t* dst;
  if (g < 393216) {
    int which = g >> 17;
    int r = g & 131071;
    src = (which == 0 ? Wq : which == 1 ? Wk : Wv) + (size_t)r * 8;
    dst = wqkv + (size_t)g * 8;
  } else if (g < 524288) {
    int r = g - 393216;
    src = Wo + (size_t)r * 8; dst = wo + (size_t)r * 8;
  } else if (g < 1048576) {
    int r = g - 524288;
    src = W1 + (size_t)r * 8; dst = w1 + (size_t)r * 8;
  } else {
    int r = g - 1048576;
    src = W2 + (size_t)r * 8; dst = w2 + (size_t)r * 8;
  }
  f32x4 a = ((const f32x4*)src)[0], b = ((const f32x4*)src)[1];
  short8 o;
#pragma unroll
  for (int e = 0; e < 4; ++e) { o[e] = (short)f2bf(a[e]); o[e + 4] = (short)f2bf(b[e]); }
  *(short8*)dst = o;
}

// ---------------------------------------------------------------------------
// GEMM256: out[M,N] = A[M,K](bf16) @ Wb[N,K](bf16)^T + bias
// BM=256, BN=128, BK=64. 512 threads = 8 waves (4m x 2n), per-wave 64x64 out.
// 3-buffer LDS ring (144KB), staged 2 tiles ahead via global_load_lds.
// Per iter: counted s_waitcnt vmcnt(6) (vmcnt(0) only on last tile) + ONE raw
// s_barrier; stage(t+2) issued after; setprio(1) around MFMA clusters.
// LDS tile layout: [row][8 chunks of 8 bf16], phys chunk = logical ^ (row&7);
// linear gload_lds dest + inverse-swizzled global source (both-sides rule).
// Grid: 1D, nwg % 8 == 0. XCD chunking: tile = (bid&7)*(nwg/8) + bid>>3,
// decoded M-major (bm = tile&31, bn = tile>>5) so each XCD reuses one B-panel.
// MODE 0: bf16 out. MODE 1: exact-erf GELU, bf16 out. MODE 2: resid(f32) +=.
// ---------------------------------------------------------------------------
template<int MODE>
__global__ __launch_bounds__(512, 1)
void gemm256(const ushort_t* __restrict__ A, const ushort_t* __restrict__ Wb,
             const float* __restrict__ bias, ushort_t* __restrict__ outb,
             float* __restrict__ resid, int K, int N)
{
  __shared__ __align__(16) ushort_t As[3][256 * 64];
  __shared__ __align__(16) ushort_t Bs[3][128 * 64];
  const int tid = threadIdx.x;
  const int lane = tid & 63, wave = tid >> 6;
  const int wm = wave >> 1, wn = wave & 1;
  const int l15 = lane & 15, l4 = lane >> 4;

  const int nwg = gridDim.x;
  const int cpx = nwg >> 3;
  const int tileid = (blockIdx.x & 7) * cpx + (blockIdx.x >> 3);
  const long bm0 = (long)(tileid & 31) * 256;   // M=8192 -> 32 M-tiles
  const long bn0 = (long)(tileid >> 5) * 128;

  f32x4 acc[4][4] = {};

  auto stage = [&](int buf, int kt) {
#pragma unroll
    for (int j = 0; j < 4; ++j) {              // A: 2048 chunks of 16B
      int cidx = j * 512 + tid;
      int row = cidx >> 3;
      int cl = (cidx & 7) ^ (row & 7);
      gload_lds16(A + (size_t)(bm0 + row) * K + kt + cl * 8, &As[buf][cidx * 8]);
    }
#pragma unroll
    for (int j = 0; j < 2; ++j) {              // B: 1024 chunks of 16B
      int cidx = j * 512 + tid;
      int row = cidx >> 3;
      int cl = (cidx & 7) ^ (row & 7);
      gload_lds16(Wb + (size_t)(bn0 + row) * K + kt + cl * 8, &Bs[buf][cidx * 8]);
    }
  };  // 6 global_load_lds per thread per stage

  const int nt = K >> 6;                        // K=1024/4096 -> nt=16/64
  stage(0, 0);
  stage(1, 64);

  for (int t = 0; t < nt; ++t) {
    if (t == nt - 1) asm volatile("s_waitcnt vmcnt(0)" ::: "memory");
    else             asm volatile("s_waitcnt vmcnt(6)" ::: "memory");
    __builtin_amdgcn_s_barrier();
    __builtin_amdgcn_sched_barrier(0);
    if (t + 2 < nt) stage((t + 2) % 3, (t + 2) << 6);
    const ushort_t* Ab = &As[t % 3][0];
    const ushort_t* Bb = &Bs[t % 3][0];
#pragma unroll
    for (int ks = 0; ks < 2; ++ks) {
      short8 af[4], bfr[4];
#pragma unroll
      for (int mi = 0; mi < 4; ++mi) {
        int row = wm * 64 + mi * 16 + l15;
        int p = (ks * 4 + l4) ^ (row & 7);
        af[mi] = *(const short8*)&Ab[row * 64 + p * 8];
      }
#pragma unroll
      for (int ni = 0; ni < 4; ++ni) {
        int row = wn * 64 + ni * 16 + l15;
        int p = (ks * 4 + l4) ^ (row & 7);
        bfr[ni] = *(const short8*)&Bb[row * 64 + p * 8];
      }
      __builtin_amdgcn_s_setprio(1);
#pragma unroll
      for (int mi = 0; mi < 4; ++mi)
#pragma unroll
        for (int ni = 0; ni < 4; ++ni)
          acc[mi][ni] = __builtin_amdgcn_mfma_f32_16x16x32_bf16(
              af[mi], bfr[ni], acc[mi][ni], 0, 0, 0);
      __builtin_amdgcn_s_setprio(0);
    }
    __builtin_amdgcn_sched_barrier(0);
  }

  // ---- epilogue ----
#pragma unroll
  for (int ni = 0; ni < 4; ++ni) {
    long col = bn0 + wn * 64 + ni * 16 + l15;
    float bv = bias[col];
#pragma unroll
    for (int mi = 0; mi < 4; ++mi) {
#pragma unroll
      for (int r = 0; r < 4; ++r) {
        long row = bm0 + wm * 64 + mi * 16 + l4 * 4 + r;
        float v = acc[mi][ni][r] + bv;
        if (MODE == 1) v = 0.5f * v * (1.0f + erff(v * 0.70710678118f));
        if (MODE == 2) {
          float* rp = resid + (size_t)row * N + col;
          *rp = *rp + v;
        } else {
          outb[(size_t)row * N + col] = f2bf(v);
        }
      }
    }
  }
}

// ---------------------------------------------------------------------------
// Fused block-causal flash attention over packed QKV [8192][3072] bf16.
// 1D grid 2048: bid = qb*128 + (b*16+h)  ->  all 16 q-tiles of one (b,h)
// land on one XCD (bid%8 == pair%8); 16 pairs/XCD * 256KB K+V = 4MB = L2.
// launch_bounds(256,4): 4 blocks/CU to hide the serial softmax/stage phases.
// ---------------------------------------------------------------------------
__global__ __launch_bounds__(256, 4)
void attn_kernel(const ushort_t* __restrict__ qkv, ushort_t* __restrict__ y)
{
  __shared__ __align__(16) ushort_t Qs[64 * 64];
  __shared__ __align__(16) ushort_t Ks[64 * 64];
  __shared__ __align__(16) ushort_t Vts[64 * 64];  // transposed: [d][kv]
  __shared__ __align__(16) ushort_t Ps[64 * 64];
  const int tid = threadIdx.x;
  const int lane = tid & 63, wave = tid >> 6;
  const int l15 = lane & 15, l4 = lane >> 4;
  const int w16 = wave * 16;
  const int bid = blockIdx.x;
  const int pair = bid & 127, qb = bid >> 7;
  const int h = pair & 15, b = pair >> 4;
  const int qoff = h * HD, koff = C + h * HD, voff = 2 * C + h * HD;
  const size_t qrow0 = (size_t)(b * T + qb * 64);

  // stage Q once
#pragma unroll
  for (int j = 0; j < 2; ++j) {
    int cidx = j * 256 + tid;
    int row = cidx >> 3, cl = (cidx & 7) ^ (row & 7);
    gload_lds16(qkv + (qrow0 + row) * CS + qoff + cl * 8, &Qs[cidx * 8]);
  }

  f32x4 o[4] = {};
  float mrun[4] = {-INFINITY, -INFINITY, -INFINITY, -INFINITY};
  float lrun[4] = {0.f, 0.f, 0.f, 0.f};

  __syncthreads();

  for (int kvb = 0; kvb <= qb; ++kvb) {
    const size_t krow0 = (size_t)(b * T + kvb * 64);
    // stage K
#pragma unroll
    for (int j = 0; j < 2; ++j) {
      int cidx = j * 256 + tid;
      int row = cidx >> 3, cl = (cidx & 7) ^ (row & 7);
      gload_lds16(qkv + (krow0 + row) * CS + koff + cl * 8, &Ks[cidx * 8]);
    }
    // stage V transposed: Vts[d][kv], swizzled
#pragma unroll
    for (int pass = 0; pass < 2; ++pass) {
      int dc = (tid >> 6) + pass * 4;
      int kvr = tid & 63;
      const ushort_t* src = qkv + (krow0 + kvr) * CS + voff + dc * 8;
      short8 vv = *(const short8*)src;
#pragma unroll
      for (int i = 0; i < 8; ++i) {
        int d = dc * 8 + i;
        Vts[d * 64 + (((kvr >> 3) ^ (d & 7)) << 3) + (kvr & 7)] = (ushort_t)vv[i];
      }
    }
    __syncthreads();

    // S = Q K^T
    f32x4 s[4] = {};
#pragma unroll
    for (int ks = 0; ks < 2; ++ks) {
      int arow = w16 + l15;
      int pa = (ks * 4 + l4) ^ (arow & 7);
      short8 aq = *(const short8*)&Qs[arow * 64 + pa * 8];
#pragma unroll
      for (int n = 0; n < 4; ++n) {
        int br = n * 16 + l15;
        int pb = (ks * 4 + l4) ^ (br & 7);
        short8 bk2 = *(const short8*)&Ks[br * 64 + pb * 8];
        s[n] = __builtin_amdgcn_mfma_f32_16x16x32_bf16(aq, bk2, s[n], 0, 0, 0);
      }
    }

    // online softmax (row reduce over 16 lanes sharing l4)
#pragma unroll
    for (int r = 0; r < 4; ++r) {
      float mx = fmaxf(fmaxf(s[0][r], s[1][r]), fmaxf(s[2][r], s[3][r]));
#pragma unroll
      for (int d = 1; d < 16; d <<= 1) mx = fmaxf(mx, __shfl_xor(mx, d, 16));
      mx *= 0.125f;  // 1/sqrt(64)
      float mnew = fmaxf(mrun[r], mx);
      float alpha = __expf(mrun[r] - mnew);
      float rowsum = 0.f;
      int qr = w16 + l4 * 4 + r;
#pragma unroll
      for (int n = 0; n < 4; ++n) {
        float pv = __expf(s[n][r] * 0.125f - mnew);
        rowsum += pv;
        int kv = n * 16 + l15;
        Ps[qr * 64 + (((kv >> 3) ^ (qr & 7)) << 3) + (kv & 7)] = f2bf(pv);
      }
#pragma unroll
      for (int d = 1; d < 16; d <<= 1) rowsum += __shfl_xor(rowsum, d, 16);
      mrun[r] = mnew;
      lrun[r] = lrun[r] * alpha + rowsum;
      o[0][r] *= alpha; o[1][r] *= alpha; o[2][r] *= alpha; o[3][r] *= alpha;
    }

    // O += P V
#pragma unroll
    for (int ks = 0; ks < 2; ++ks) {
      int arow = w16 + l15;
      int pa = (ks * 4 + l4) ^ (arow & 7);
      short8 ap = *(const short8*)&Ps[arow * 64 + pa * 8];
#pragma unroll
      for (int n = 0; n < 4; ++n) {
        int vr = n * 16 + l15;
        int pb = (ks * 4 + l4) ^ (vr & 7);
        short8 bvv = *(const short8*)&Vts[vr * 64 + pb * 8];
        o[n] = __builtin_amdgcn_mfma_f32_16x16x32_bf16(ap, bvv, o[n], 0, 0, 0);
      }
    }
    __syncthreads();
  }

  // write y (bf16, stride C)
#pragma unroll
  for (int n = 0; n < 4; ++n) {
#pragma unroll
    for (int r = 0; r < 4; ++r) {
      float val = o[n][r] / lrun[r];
      y[(qrow0 + w16 + l4 * 4 + r) * C + h * HD + n * 16 + l15] = f2bf(val);
    }
  }
}

// ---------------------------------------------------------------------------
// LayerNorm over C=1024. One block (256 thr) per row.
// ---------------------------------------------------------------------------
template<int OUTBF16>
__global__ __launch_bounds__(256, 4)
void ln_kernel(const float* __restrict__ x, const float* __restrict__ w,
               const float* __restrict__ bprm, void* __restrict__ out)
{
  const size_t row = blockIdx.x;
  const int tid = threadIdx.x;
  f32x4 xv = ((const f32x4*)(x + row * 1024))[tid];
  float s1 = xv[0] + xv[1] + xv[2] + xv[3];
  float s2 = xv[0] * xv[0] + xv[1] * xv[1] + xv[2] * xv[2] + xv[3] * xv[3];
#pragma unroll
  for (int m = 1; m < 64; m <<= 1) {
    s1 += __shfl_xor(s1, m);
    s2 += __shfl_xor(s2, m);
  }
  __shared__ float red[8];
  const int wave = tid >> 6, lane = tid & 63;
  if (lane == 0) { red[wave * 2] = s1; red[wave * 2 + 1] = s2; }
  __syncthreads();
  s1 = red[0] + red[2] + red[4] + red[6];
  s2 = red[1] + red[3] + red[5] + red[7];
  const float mean = s1 * (1.f / 1024.f);
  const float var = s2 * (1.f / 1024.f) - mean * mean;
  const float rstd = rsqrtf(var + 1e-5f);
  f32x4 wv = ((const f32x4*)w)[tid];
  f32x4 bv = ((const f32x4*)bprm)[tid];
  f32x4 ov;
#pragma unroll
  for (int c2 = 0; c2 < 4; ++c2) ov[c2] = (xv[c2] - mean) * rstd * wv[c2] + bv[c2];
  if (OUTBF16) {
    ushort4 u;
    u.x = f2bf(ov[0]); u.y = f2bf(ov[1]); u.z = f2bf(ov[2]); u.w = f2bf(ov[3]);
    ((ushort4*)out)[row * 256 + tid] = u;
  } else {
    ((f32x4*)out)[row * 256 + tid] = ov;
  }
}

// ---------------------------------------------------------------------------
extern "C" void kernel_launch(void* const* d_in, const int* in_sizes, int n_in,
                              void* d_out, int out_size, void* d_ws, size_t ws_size,
                              hipStream_t stream)
{
  const float* seq  = (const float*)d_in[0];
  const float* Wq   = (const float*)d_in[2];  const float* bq = (const float*)d_in[3];
  const float* Wk   = (const float*)d_in[4];  const float* bk = (const float*)d_in[5];
  const float* Wv   = (const float*)d_in[6];  const float* bv = (const float*)d_in[7];
  const float* Wo   = (const float*)d_in[8];  const float* bo = (const float*)d_in[9];
  const float* ln1w = (const float*)d_in[10]; const float* ln1b = (const float*)d_in[11];
  const float* ln2w = (const float*)d_in[12]; const float* ln2b = (const float*)d_in[13];
  const float* W1   = (const float*)d_in[14]; const float* b1 = (const float*)d_in[15];
  const float* W2   = (const float*)d_in[16]; const float* b2 = (const float*)d_in[17];
  const float* lnfw = (const float*)d_in[18]; const float* lnfb = (const float*)d_in[19];

  char* ws = (char*)d_ws;
  size_t off = 0;
  float* X = (float*)(ws + off);         off += (size_t)MROWS * C * 4;       // 32MB residual
  ushort_t* Hb = (ushort_t*)(ws + off);  off += (size_t)MROWS * C * 2;       // 16MB ln out
  ushort_t* Yb = (ushort_t*)(ws + off);  off += (size_t)MROWS * C * 2;       // 16MB attn out
  ushort_t* BIG = (ushort_t*)(ws + off); off += (size_t)MROWS * 4 * C * 2;   // 64MB QKV|gelu
  ushort_t* wqkv = (ushort_t*)(ws + off); off += (size_t)3 * C * C * 2;      // 6MB
  ushort_t* wo   = (ushort_t*)(ws + off); off += (size_t)C * C * 2;          // 2MB
  ushort_t* w1   = (ushort_t*)(ws + off); off += (size_t)4 * C * C * 2;      // 8MB
  ushort_t* w2   = (ushort_t*)(ws + off); off += (size_t)4 * C * C * 2;      // 8MB
  float* bqkv = (float*)(ws + off);       off += (size_t)3 * C * 4;          // 12KB
  ushort_t* QKVb = BIG;   // [8192][3072], live qkv-gemm -> attn
  ushort_t* Gb = BIG;     // [8192][4096], live w1 -> w2

  hipMemcpyAsync(X, seq, (size_t)MROWS * C * 4, hipMemcpyDeviceToDevice, stream);

  const dim3 blk(256);
  const dim3 blk512(512);
  const dim3 gQKV(768);     // 32 M-tiles x 24 N-tiles
  const dim3 gN1024(256);   // 32 x 8
  const dim3 gN4096(1024);  // 32 x 32
  const dim3 gAttn(2048);
  const dim3 gConv(6145);

  for (int i = 0; i < NL; ++i) {
    const size_t w1Off = (size_t)i * C * C;
    const size_t w4Off = (size_t)i * 4 * C * C;
    convw_kernel<<<gConv, blk, 0, stream>>>(Wq + w1Off, Wk + w1Off, Wv + w1Off,
                                            Wo + w1Off, W1 + w4Off, W2 + w4Off,
                                            bq + i * C, bk + i * C, bv + i * C,
                                            wqkv, wo, w1, w2, bqkv);
    ln_kernel<1><<<MROWS, blk, 0, stream>>>(X, ln1w + i * C, ln1b + i * C, Hb);
    gemm256<0><<<gQKV, blk512, 0, stream>>>(Hb, wqkv, bqkv, QKVb, nullptr, C, CS);
    attn_kernel<<<gAttn, blk, 0, stream>>>(QKVb, Yb);
    gemm256<2><<<gN1024, blk512, 0, stream>>>(Yb, wo, bo + i * C, nullptr, X, C, C);
    ln_kernel<1><<<MROWS, blk, 0, stream>>>(X, ln2w + i * C, ln2b + i * C, Hb);
    gemm256<1><<<gN4096, blk512, 0, stream>>>(Hb, w1, b1 + (size_t)i * 4 * C, Gb, nullptr, C, 4 * C);
    gemm256<2><<<gN1024, blk512, 0, stream>>>(Gb, w2, b2 + i * C, nullptr, X, 4 * C, C);
  }
  ln_kernel<0><<<MROWS, blk, 0, stream>>>(X, lnfw, lnfb, (float*)d_out);
}

// Round 4
// 3200.057 us; speedup vs baseline: 1.2004x; 1.2004x over previous
//
#include <hip/hip_runtime.h>
#include <math.h>

typedef unsigned short ushort_t;
typedef __attribute__((ext_vector_type(4))) float f32x4;
typedef __attribute__((ext_vector_type(8))) short short8;

constexpr int BATCH = 8, T = 1024, C = 1024, NH = 16, HD = 64, NL = 8;
constexpr int MROWS = BATCH * T;  // 8192
constexpr int CS = 3 * C;         // packed QKV row stride

#define WAITVM(n) asm volatile("s_waitcnt vmcnt(" #n ")" ::: "memory")

__device__ __forceinline__ ushort_t f2bf(float f) {
  unsigned u = __builtin_bit_cast(unsigned, f);
  u += 0x7fffu + ((u >> 16) & 1u);
  return (ushort_t)(u >> 16);
}

__device__ __forceinline__ void gload_lds16(const ushort_t* g, ushort_t* l) {
  __builtin_amdgcn_global_load_lds(
      (const __attribute__((address_space(1))) unsigned int*)g,
      (__attribute__((address_space(3))) unsigned int*)l, 16, 0, 0);
}

// ---------------------------------------------------------------------------
// Per-layer weight conversion f32->bf16 + QKV packing.
// ---------------------------------------------------------------------------
__global__ __launch_bounds__(256, 8)
void convw_kernel(const float* __restrict__ Wq, const float* __restrict__ Wk,
                  const float* __restrict__ Wv, const float* __restrict__ Wo,
                  const float* __restrict__ W1, const float* __restrict__ W2,
                  const float* __restrict__ bq, const float* __restrict__ bk,
                  const float* __restrict__ bv,
                  ushort_t* __restrict__ wqkv, ushort_t* __restrict__ wo,
                  ushort_t* __restrict__ w1, ushort_t* __restrict__ w2,
                  float* __restrict__ bqkv)
{
  if (blockIdx.x == 6144) {
    int t = threadIdx.x;
    if (t < 384) {
      const float* s = (t < 128) ? (bq + t * 8)
                     : (t < 256) ? (bk + (t - 128) * 8)
                                 : (bv + (t - 256) * 8);
      f32x4 a = ((const f32x4*)s)[0], b = ((const f32x4*)s)[1];
      ((f32x4*)(bqkv + t * 8))[0] = a;
      ((f32x4*)(bqkv + t * 8))[1] = b;
    }
    return;
  }
  int g = blockIdx.x * 256 + threadIdx.x;
  const float* src;
  ushort_t* dst;
  if (g < 393216) {
    int which = g >> 17;
    int r = g & 131071;
    src = (which == 0 ? Wq : which == 1 ? Wk : Wv) + (size_t)r * 8;
    dst = wqkv + (size_t)g * 8;
  } else if (g < 524288) {
    int r = g - 393216;
    src = Wo + (size_t)r * 8; dst = wo + (size_t)r * 8;
  } else if (g < 1048576) {
    int r = g - 524288;
    src = W1 + (size_t)r * 8; dst = w1 + (size_t)r * 8;
  } else {
    int r = g - 1048576;
    src = W2 + (size_t)r * 8; dst = w2 + (size_t)r * 8;
  }
  f32x4 a = ((const f32x4*)src)[0], b = ((const f32x4*)src)[1];
  short8 o;
#pragma unroll
  for (int e = 0; e < 4; ++e) { o[e] = (short)f2bf(a[e]); o[e + 4] = (short)f2bf(b[e]); }
  *(short8*)dst = o;
}

// ---------------------------------------------------------------------------
// GEMM: out[M,N] = A[M,K](bf16) @ Wb[N,K](bf16)^T + bias
// BM=256, BN=NB (256 or 128), BK=32. 512 thr = 8 waves.
//   NB=256: waves 2m x 4n, per-wave out 128x64 (acc[8][4]); L=4 loads/stage.
//   NB=128: waves 4m x 2n, per-wave out  64x64 (acc[4][4]); L=3 loads/stage.
// 4-buffer LDS ring, staged 3 K-tiles ahead via global_load_lds.
// Phase t: {ds_read frags(t); stage(t+3); MFMA; vmcnt(2L) ensures tile t+1
// landed (per-wave count -> globalized by the following s_barrier); barrier}.
// Never drains vmcnt in steady state. WAR safe: stage(t+3) overwrites buffer
// (t-1)&3, whose readers finished before the end-of-(t-1) barrier.
// LDS tile [row][4 chunks of 8 bf16]; phys chunk = (logical + (row>>1)) & 3
// -> 2-way bank aliasing (free). Linear gload_lds dest + inverse-swizzled
// global source (both-sides rule).
// XCD decode: xcd = bid&7 owns 4 contiguous bm panels x all bn (bn-fast):
// A panels stay L2-resident, B streams from L3. Requires grid = 32*nbn, %8==0.
// MODE 0: bf16 out. MODE 1: exact-erf GELU, bf16 out. MODE 2: resid(f32) +=.
// ---------------------------------------------------------------------------
template<int MODE, int NB>
__global__ __launch_bounds__(512, 1)
void gemmk(const ushort_t* __restrict__ A, const ushort_t* __restrict__ Wb,
           const float* __restrict__ bias, ushort_t* __restrict__ outb,
           float* __restrict__ resid, int K, int N, int nbn)
{
  constexpr int MI = (NB == 256) ? 8 : 4;       // m-frags per wave
  constexpr int NI = 4;                          // n-frags per wave
  constexpr int WAVE_M = MI * 16;
  constexpr int NBJ = (NB == 256) ? 2 : 1;       // B stage loads per thread
  constexpr int AT = 256 * 32;                   // A tile ushorts (16KB)
  constexpr int BT = NB * 32;                    // B tile ushorts

  __shared__ __align__(16) ushort_t As[4 * AT];
  __shared__ __align__(16) ushort_t Bs[4 * BT];

  const int tid = threadIdx.x;
  const int lane = tid & 63, wave = tid >> 6;
  const int wm = (NB == 256) ? (wave >> 2) : (wave >> 1);
  const int wn = (NB == 256) ? (wave & 3) : (wave & 1);
  const int l15 = lane & 15, l4 = lane >> 4;

  const int cpx = gridDim.x >> 3;
  const int xcd = blockIdx.x & 7;
  const int local = blockIdx.x >> 3;
  const int bm = xcd * 4 + local / nbn;          // cpx == 4*nbn always
  const int bn = local % nbn;
  const long bm0 = (long)bm * 256;
  const long bn0 = (long)bn * NB;

  // ---- per-thread stage sources (inverse-swizzled) and LDS dest offsets ----
  const ushort_t* srcA[2]; int dA[2];
#pragma unroll
  for (int j = 0; j < 2; ++j) {
    int cidx = j * 512 + tid;                    // 1024 chunks of 16B
    int row = cidx >> 2, c = cidx & 3;
    int cl = (c - (row >> 1)) & 3;
    srcA[j] = A + (size_t)(bm0 + row) * K + cl * 8;
    dA[j] = cidx * 8;
  }
  const ushort_t* srcB[NBJ]; int dB[NBJ];
#pragma unroll
  for (int j = 0; j < NBJ; ++j) {
    int cidx = j * 512 + tid;
    int row = cidx >> 2, c = cidx & 3;
    int cl = (c - (row >> 1)) & 3;
    srcB[j] = Wb + (size_t)(bn0 + row) * K + cl * 8;
    dB[j] = cidx * 8;
  }

  // ---- per-thread fragment LDS offsets (swizzled reads) ----
  int aoff[MI], boff[NI];
#pragma unroll
  for (int mi = 0; mi < MI; ++mi) {
    int row = wm * WAVE_M + mi * 16 + l15;
    int p = (l4 + (row >> 1)) & 3;
    aoff[mi] = row * 32 + p * 8;
  }
#pragma unroll
  for (int ni = 0; ni < NI; ++ni) {
    int row = wn * 64 + ni * 16 + l15;
    int p = (l4 + (row >> 1)) & 3;
    boff[ni] = row * 32 + p * 8;
  }

  auto stage = [&](int buf, int kt) {
#pragma unroll
    for (int j = 0; j < 2; ++j)
      gload_lds16(srcA[j] + kt, &As[buf * AT + dA[j]]);
#pragma unroll
    for (int j = 0; j < NBJ; ++j)
      gload_lds16(srcB[j] + kt, &Bs[buf * BT + dB[j]]);
  };

  f32x4 acc[MI][NI] = {};
  const int nt = K >> 5;

  stage(0, 0); stage(1, 32); stage(2, 64);
  if (NB == 256) WAITVM(8); else WAITVM(6);      // tile 0 landed
  __builtin_amdgcn_s_barrier();

  for (int t = 0; t < nt; ++t) {
    const ushort_t* Ab = &As[(t & 3) * AT];
    const ushort_t* Bb = &Bs[(t & 3) * BT];
    short8 af[MI], bf[NI];
#pragma unroll
    for (int mi = 0; mi < MI; ++mi) af[mi] = *(const short8*)&Ab[aoff[mi]];
#pragma unroll
    for (int ni = 0; ni < NI; ++ni) bf[ni] = *(const short8*)&Bb[boff[ni]];

    if (t + 3 < nt) stage((t + 3) & 3, (t + 3) << 5);
    __builtin_amdgcn_sched_barrier(0);

    __builtin_amdgcn_s_setprio(1);
#pragma unroll
    for (int mi = 0; mi < MI; ++mi)
#pragma unroll
      for (int ni = 0; ni < NI; ++ni)
        acc[mi][ni] = __builtin_amdgcn_mfma_f32_16x16x32_bf16(
            af[mi], bf[ni], acc[mi][ni], 0, 0, 0);
    __builtin_amdgcn_s_setprio(0);

    // ensure tile t+1 is fully in LDS before the barrier releases readers
    const int rem2 = nt - 2 - t;
    if (rem2 >= 2)      { if (NB == 256) WAITVM(8); else WAITVM(6); }
    else if (rem2 == 1) { if (NB == 256) WAITVM(4); else WAITVM(3); }
    else if (rem2 == 0) { WAITVM(0); }
    __builtin_amdgcn_s_barrier();
  }

  // ---- epilogue ----
#pragma unroll
  for (int ni = 0; ni < NI; ++ni) {
    long col = bn0 + wn * 64 + ni * 16 + l15;
    float bv = bias[col];
#pragma unroll
    for (int mi = 0; mi < MI; ++mi) {
#pragma unroll
      for (int r = 0; r < 4; ++r) {
        long row = bm0 + wm * WAVE_M + mi * 16 + l4 * 4 + r;
        float v = acc[mi][ni][r] + bv;
        if (MODE == 1) v = 0.5f * v * (1.0f + erff(v * 0.70710678118f));
        if (MODE == 2) {
          float* rp = resid + (size_t)row * N + col;
          *rp = *rp + v;
        } else {
          outb[(size_t)row * N + col] = f2bf(v);
        }
      }
    }
  }
}

// ---------------------------------------------------------------------------
// Fused block-causal flash attention over packed QKV [8192][3072] bf16.
// 1D grid 2048: bid = qb*128 + (b*16+h); 4 blocks/CU.
// ---------------------------------------------------------------------------
__global__ __launch_bounds__(256, 4)
void attn_kernel(const ushort_t* __restrict__ qkv, ushort_t* __restrict__ y)
{
  __shared__ __align__(16) ushort_t Qs[64 * 64];
  __shared__ __align__(16) ushort_t Ks[64 * 64];
  __shared__ __align__(16) ushort_t Vts[64 * 64];  // transposed: [d][kv]
  __shared__ __align__(16) ushort_t Ps[64 * 64];
  const int tid = threadIdx.x;
  const int lane = tid & 63, wave = tid >> 6;
  const int l15 = lane & 15, l4 = lane >> 4;
  const int w16 = wave * 16;
  const int bid = blockIdx.x;
  const int pair = bid & 127, qb = bid >> 7;
  const int h = pair & 15, b = pair >> 4;
  const int qoff = h * HD, koff = C + h * HD, voff = 2 * C + h * HD;
  const size_t qrow0 = (size_t)(b * T + qb * 64);

#pragma unroll
  for (int j = 0; j < 2; ++j) {
    int cidx = j * 256 + tid;
    int row = cidx >> 3, cl = (cidx & 7) ^ (row & 7);
    gload_lds16(qkv + (qrow0 + row) * CS + qoff + cl * 8, &Qs[cidx * 8]);
  }

  f32x4 o[4] = {};
  float mrun[4] = {-INFINITY, -INFINITY, -INFINITY, -INFINITY};
  float lrun[4] = {0.f, 0.f, 0.f, 0.f};

  __syncthreads();

  for (int kvb = 0; kvb <= qb; ++kvb) {
    const size_t krow0 = (size_t)(b * T + kvb * 64);
#pragma unroll
    for (int j = 0; j < 2; ++j) {
      int cidx = j * 256 + tid;
      int row = cidx >> 3, cl = (cidx & 7) ^ (row & 7);
      gload_lds16(qkv + (krow0 + row) * CS + koff + cl * 8, &Ks[cidx * 8]);
    }
#pragma unroll
    for (int pass = 0; pass < 2; ++pass) {
      int dc = (tid >> 6) + pass * 4;
      int kvr = tid & 63;
      const ushort_t* src = qkv + (krow0 + kvr) * CS + voff + dc * 8;
      short8 vv = *(const short8*)src;
#pragma unroll
      for (int i = 0; i < 8; ++i) {
        int d = dc * 8 + i;
        Vts[d * 64 + (((kvr >> 3) ^ (d & 7)) << 3) + (kvr & 7)] = (ushort_t)vv[i];
      }
    }
    __syncthreads();

    f32x4 s[4] = {};
#pragma unroll
    for (int ks = 0; ks < 2; ++ks) {
      int arow = w16 + l15;
      int pa = (ks * 4 + l4) ^ (arow & 7);
      short8 aq = *(const short8*)&Qs[arow * 64 + pa * 8];
#pragma unroll
      for (int n = 0; n < 4; ++n) {
        int br = n * 16 + l15;
        int pb = (ks * 4 + l4) ^ (br & 7);
        short8 bk2 = *(const short8*)&Ks[br * 64 + pb * 8];
        s[n] = __builtin_amdgcn_mfma_f32_16x16x32_bf16(aq, bk2, s[n], 0, 0, 0);
      }
    }

#pragma unroll
    for (int r = 0; r < 4; ++r) {
      float mx = fmaxf(fmaxf(s[0][r], s[1][r]), fmaxf(s[2][r], s[3][r]));
#pragma unroll
      for (int d = 1; d < 16; d <<= 1) mx = fmaxf(mx, __shfl_xor(mx, d, 16));
      mx *= 0.125f;
      float mnew = fmaxf(mrun[r], mx);
      float alpha = __expf(mrun[r] - mnew);
      float rowsum = 0.f;
      int qr = w16 + l4 * 4 + r;
#pragma unroll
      for (int n = 0; n < 4; ++n) {
        float pv = __expf(s[n][r] * 0.125f - mnew);
        rowsum += pv;
        int kv = n * 16 + l15;
        Ps[qr * 64 + (((kv >> 3) ^ (qr & 7)) << 3) + (kv & 7)] = f2bf(pv);
      }
#pragma unroll
      for (int d = 1; d < 16; d <<= 1) rowsum += __shfl_xor(rowsum, d, 16);
      mrun[r] = mnew;
      lrun[r] = lrun[r] * alpha + rowsum;
      o[0][r] *= alpha; o[1][r] *= alpha; o[2][r] *= alpha; o[3][r] *= alpha;
    }

#pragma unroll
    for (int ks = 0; ks < 2; ++ks) {
      int arow = w16 + l15;
      int pa = (ks * 4 + l4) ^ (arow & 7);
      short8 ap = *(const short8*)&Ps[arow * 64 + pa * 8];
#pragma unroll
      for (int n = 0; n < 4; ++n) {
        int vr = n * 16 + l15;
        int pb = (ks * 4 + l4) ^ (vr & 7);
        short8 bvv = *(const short8*)&Vts[vr * 64 + pb * 8];
        o[n] = __builtin_amdgcn_mfma_f32_16x16x32_bf16(ap, bvv, o[n], 0, 0, 0);
      }
    }
    __syncthreads();
  }

#pragma unroll
  for (int n = 0; n < 4; ++n) {
#pragma unroll
    for (int r = 0; r < 4; ++r) {
      float val = o[n][r] / lrun[r];
      y[(qrow0 + w16 + l4 * 4 + r) * C + h * HD + n * 16 + l15] = f2bf(val);
    }
  }
}

// ---------------------------------------------------------------------------
// LayerNorm over C=1024. One block (256 thr) per row.
// ---------------------------------------------------------------------------
template<int OUTBF16>
__global__ __launch_bounds__(256, 4)
void ln_kernel(const float* __restrict__ x, const float* __restrict__ w,
               const float* __restrict__ bprm, void* __restrict__ out)
{
  const size_t row = blockIdx.x;
  const int tid = threadIdx.x;
  f32x4 xv = ((const f32x4*)(x + row * 1024))[tid];
  float s1 = xv[0] + xv[1] + xv[2] + xv[3];
  float s2 = xv[0] * xv[0] + xv[1] * xv[1] + xv[2] * xv[2] + xv[3] * xv[3];
#pragma unroll
  for (int m = 1; m < 64; m <<= 1) {
    s1 += __shfl_xor(s1, m);
    s2 += __shfl_xor(s2, m);
  }
  __shared__ float red[8];
  const int wave = tid >> 6, lane = tid & 63;
  if (lane == 0) { red[wave * 2] = s1; red[wave * 2 + 1] = s2; }
  __syncthreads();
  s1 = red[0] + red[2] + red[4] + red[6];
  s2 = red[1] + red[3] + red[5] + red[7];
  const float mean = s1 * (1.f / 1024.f);
  const float var = s2 * (1.f / 1024.f) - mean * mean;
  const float rstd = rsqrtf(var + 1e-5f);
  f32x4 wv = ((const f32x4*)w)[tid];
  f32x4 bv = ((const f32x4*)bprm)[tid];
  f32x4 ov;
#pragma unroll
  for (int c2 = 0; c2 < 4; ++c2) ov[c2] = (xv[c2] - mean) * rstd * wv[c2] + bv[c2];
  if (OUTBF16) {
    ushort4 u;
    u.x = f2bf(ov[0]); u.y = f2bf(ov[1]); u.z = f2bf(ov[2]); u.w = f2bf(ov[3]);
    ((ushort4*)out)[row * 256 + tid] = u;
  } else {
    ((f32x4*)out)[row * 256 + tid] = ov;
  }
}

// ---------------------------------------------------------------------------
extern "C" void kernel_launch(void* const* d_in, const int* in_sizes, int n_in,
                              void* d_out, int out_size, void* d_ws, size_t ws_size,
                              hipStream_t stream)
{
  const float* seq  = (const float*)d_in[0];
  const float* Wq   = (const float*)d_in[2];  const float* bq = (const float*)d_in[3];
  const float* Wk   = (const float*)d_in[4];  const float* bk = (const float*)d_in[5];
  const float* Wv   = (const float*)d_in[6];  const float* bv = (const float*)d_in[7];
  const float* Wo   = (const float*)d_in[8];  const float* bo = (const float*)d_in[9];
  const float* ln1w = (const float*)d_in[10]; const float* ln1b = (const float*)d_in[11];
  const float* ln2w = (const float*)d_in[12]; const float* ln2b = (const float*)d_in[13];
  const float* W1   = (const float*)d_in[14]; const float* b1 = (const float*)d_in[15];
  const float* W2   = (const float*)d_in[16]; const float* b2 = (const float*)d_in[17];
  const float* lnfw = (const float*)d_in[18]; const float* lnfb = (const float*)d_in[19];

  char* ws = (char*)d_ws;
  size_t off = 0;
  float* X = (float*)(ws + off);         off += (size_t)MROWS * C * 4;       // 32MB residual
  ushort_t* Hb = (ushort_t*)(ws + off);  off += (size_t)MROWS * C * 2;       // 16MB ln out
  ushort_t* Yb = (ushort_t*)(ws + off);  off += (size_t)MROWS * C * 2;       // 16MB attn out
  ushort_t* BIG = (ushort_t*)(ws + off); off += (size_t)MROWS * 4 * C * 2;   // 64MB QKV|gelu
  ushort_t* wqkv = (ushort_t*)(ws + off); off += (size_t)3 * C * C * 2;      // 6MB
  ushort_t* wo   = (ushort_t*)(ws + off); off += (size_t)C * C * 2;          // 2MB
  ushort_t* w1   = (ushort_t*)(ws + off); off += (size_t)4 * C * C * 2;      // 8MB
  ushort_t* w2   = (ushort_t*)(ws + off); off += (size_t)4 * C * C * 2;      // 8MB
  float* bqkv = (float*)(ws + off);       off += (size_t)3 * C * 4;          // 12KB
  ushort_t* QKVb = BIG;   // [8192][3072], live qkv-gemm -> attn
  ushort_t* Gb = BIG;     // [8192][4096], live w1 -> w2

  hipMemcpyAsync(X, seq, (size_t)MROWS * C * 4, hipMemcpyDeviceToDevice, stream);

  const dim3 blk(256);
  const dim3 blk512(512);
  const dim3 gQKV(384);     // 32 bm x 12 bn (BN=256)
  const dim3 gN1024(256);   // 32 bm x  8 bn (BN=128)
  const dim3 gN4096(512);   // 32 bm x 16 bn (BN=256)
  const dim3 gAttn(2048);
  const dim3 gConv(6145);

  for (int i = 0; i < NL; ++i) {
    const size_t w1Off = (size_t)i * C * C;
    const size_t w4Off = (size_t)i * 4 * C * C;
    convw_kernel<<<gConv, blk, 0, stream>>>(Wq + w1Off, Wk + w1Off, Wv + w1Off,
                                            Wo + w1Off, W1 + w4Off, W2 + w4Off,
                                            bq + i * C, bk + i * C, bv + i * C,
                                            wqkv, wo, w1, w2, bqkv);
    ln_kernel<1><<<MROWS, blk, 0, stream>>>(X, ln1w + i * C, ln1b + i * C, Hb);
    gemmk<0, 256><<<gQKV, blk512, 0, stream>>>(Hb, wqkv, bqkv, QKVb, nullptr, C, CS, 12);
    attn_kernel<<<gAttn, blk, 0, stream>>>(QKVb, Yb);
    gemmk<2, 128><<<gN1024, blk512, 0, stream>>>(Yb, wo, bo + i * C, nullptr, X, C, C, 8);
    ln_kernel<1><<<MROWS, blk, 0, stream>>>(X, ln2w + i * C, ln2b + i * C, Hb);
    gemmk<1, 256><<<gN4096, blk512, 0, stream>>>(Hb, w1, b1 + (size_t)i * 4 * C, Gb, nullptr, C, 4 * C, 16);
    gemmk<2, 128><<<gN1024, blk512, 0, stream>>>(Gb, w2, b2 + i * C, nullptr, X, 4 * C, C, 8);
  }
  ln_kernel<0><<<MROWS, blk, 0, stream>>>(X, lnfw, lnfb, (float*)d_out);
}

// Round 5
// 3180.550 us; speedup vs baseline: 1.2077x; 1.0061x over previous
//
#include <hip/hip_runtime.h>
#include <math.h>

typedef unsigned short ushort_t;
typedef __attribute__((ext_vector_type(4))) float f32x4;
typedef __attribute__((ext_vector_type(8))) short short8;

constexpr int BATCH = 8, T = 1024, C = 1024, NH = 16, HD = 64, NL = 8;
constexpr int MROWS = BATCH * T;  // 8192
constexpr int CS = 3 * C;         // packed QKV row stride

#define WAITVM0 asm volatile("s_waitcnt vmcnt(0)" ::: "memory")
#define WAITVM4 asm volatile("s_waitcnt vmcnt(4)" ::: "memory")
#define WAITVM6 asm volatile("s_waitcnt vmcnt(6)" ::: "memory")

__device__ __forceinline__ ushort_t f2bf(float f) {
  unsigned u = __builtin_bit_cast(unsigned, f);
  u += 0x7fffu + ((u >> 16) & 1u);
  return (ushort_t)(u >> 16);
}

__device__ __forceinline__ void gload_lds16(const ushort_t* g, ushort_t* l) {
  __builtin_amdgcn_global_load_lds(
      (const __attribute__((address_space(1))) unsigned int*)g,
      (__attribute__((address_space(3))) unsigned int*)l, 16, 0, 0);
}

// ---------------------------------------------------------------------------
// Per-layer weight conversion f32->bf16 + QKV packing.
// ---------------------------------------------------------------------------
__global__ __launch_bounds__(256, 8)
void convw_kernel(const float* __restrict__ Wq, const float* __restrict__ Wk,
                  const float* __restrict__ Wv, const float* __restrict__ Wo,
                  const float* __restrict__ W1, const float* __restrict__ W2,
                  const float* __restrict__ bq, const float* __restrict__ bk,
                  const float* __restrict__ bv,
                  ushort_t* __restrict__ wqkv, ushort_t* __restrict__ wo,
                  ushort_t* __restrict__ w1, ushort_t* __restrict__ w2,
                  float* __restrict__ bqkv)
{
  if (blockIdx.x == 6144) {
    int t = threadIdx.x;
    if (t < 384) {
      const float* s = (t < 128) ? (bq + t * 8)
                     : (t < 256) ? (bk + (t - 128) * 8)
                                 : (bv + (t - 256) * 8);
      f32x4 a = ((const f32x4*)s)[0], b = ((const f32x4*)s)[1];
      ((f32x4*)(bqkv + t * 8))[0] = a;
      ((f32x4*)(bqkv + t * 8))[1] = b;
    }
    return;
  }
  int g = blockIdx.x * 256 + threadIdx.x;
  const float* src;
  ushort_t* dst;
  if (g < 393216) {
    int which = g >> 17;
    int r = g & 131071;
    src = (which == 0 ? Wq : which == 1 ? Wk : Wv) + (size_t)r * 8;
    dst = wqkv + (size_t)g * 8;
  } else if (g < 524288) {
    int r = g - 393216;
    src = Wo + (size_t)r * 8; dst = wo + (size_t)r * 8;
  } else if (g < 1048576) {
    int r = g - 524288;
    src = W1 + (size_t)r * 8; dst = w1 + (size_t)r * 8;
  } else {
    int r = g - 1048576;
    src = W2 + (size_t)r * 8; dst = w2 + (size_t)r * 8;
  }
  f32x4 a = ((const f32x4*)src)[0], b = ((const f32x4*)src)[1];
  short8 o;
#pragma unroll
  for (int e = 0; e < 4; ++e) { o[e] = (short)f2bf(a[e]); o[e + 4] = (short)f2bf(b[e]); }
  *(short8*)dst = o;
}

// ---------------------------------------------------------------------------
// 8-phase GEMM: out[M,N] = A[M,K](bf16) @ Wb[N,K](bf16)^T + bias
// BM in {256,128}, BN=256, BK=64 per K-tile, 512 thr = 8 waves (2m x 4n),
// per-wave out (BM/2) x 64. LDS: 2 K-buffers x 2 k-halves per matrix.
// Half-tile staging units (16KB B / 8*LA KB A), one staged per phase,
// running 1.75 K-tiles ahead; ONE counted vmcnt per K-tile (phase 3):
//   allow = units {t+2: A-kh0, B-kh0, A-kh1} = 2+2*LA loads (6 / 4);
//   vmcnt(0) only at t==nt-2. Never drains in steady state (T3+T4).
// Phases per tile: (kh0,ni01)(kh0,ni23)(kh1,ni01)(kh1,ni23); A-frags held
// in regs across the two ni-phases. 2 raw barriers/phase; sched_barrier(0)
// after each barrier pins stage issues below the barrier (WAR ring proof).
// Swizzle: phys chunk = (logical + (row>>1)) & 3 within each 32-k half
// (round-4 validated: 0 bank conflicts); linear gload_lds dest +
// inverse-swizzled global source.
// Epilogue: per-wave LDS transpose -> 16B short8 stores (full 128B lines),
// MODE 2 -> vectorized f32x4 resid RMW. MODE 1 -> exact-erf GELU.
// XCD decode: xcd owns (BMT/8) contiguous bm panels x all bn (bn-fast).
// ---------------------------------------------------------------------------
template<int MODE, int BM>
__global__ __launch_bounds__(512, 2)
void gemm8p(const ushort_t* __restrict__ A, const ushort_t* __restrict__ Wb,
            const float* __restrict__ bias, ushort_t* __restrict__ outb,
            float* __restrict__ resid, int K, int N, int nbn)
{
  constexpr int MI = BM / 32;          // m-frags per wave (8 or 4)
  constexpr int LA = BM / 128;         // A loads/thread per half-unit (2 or 1)
  constexpr int AKH = BM * 32;         // ushorts per A kh-region
  constexpr int ABUF = 2 * AKH;
  constexpr int BKH = 256 * 32;
  constexpr int BBUF = 2 * BKH;
  constexpr int BMT = 8192 / BM;

  __shared__ __align__(16) ushort_t As[2 * ABUF];
  __shared__ __align__(16) ushort_t Bs[2 * BBUF];

  const int tid = threadIdx.x;
  const int lane = tid & 63, wave = tid >> 6;
  const int wm = wave >> 2, wn = wave & 3;
  const int l15 = lane & 15, l4 = lane >> 4;

  const int xcd = blockIdx.x & 7;
  const int local = blockIdx.x >> 3;
  const int bm = xcd * (BMT / 8) + local / nbn;
  const int bn = local % nbn;
  const long bm0 = (long)bm * BM;
  const long bn0 = (long)bn * 256;

  // ---- staging sources (inverse-swizzled) + LDS dest offsets ----
  const ushort_t* srcA[LA]; int dA[LA];
#pragma unroll
  for (int j = 0; j < LA; ++j) {
    int cidx = j * 512 + tid;
    int row = cidx >> 2, c = cidx & 3;
    int cl = (c - (row >> 1)) & 3;
    srcA[j] = A + (size_t)(bm0 + row) * K + cl * 8;
    dA[j] = cidx * 8;
  }
  const ushort_t* srcB[2]; int dB[2];
#pragma unroll
  for (int j = 0; j < 2; ++j) {
    int cidx = j * 512 + tid;
    int row = cidx >> 2, c = cidx & 3;
    int cl = (c - (row >> 1)) & 3;
    srcB[j] = Wb + (size_t)(bn0 + row) * K + cl * 8;
    dB[j] = cidx * 8;
  }

  // stage one half-tile unit u: tile u>>2, part u&3 (0=Akh0,1=Bkh0,2=Akh1,3=Bkh1)
  auto stage_unit = [&](int u) {
    int tau = u >> 2, part = u & 3;
    int buf = tau & 1, kh = part >> 1;
    int kt = (tau << 6) + (kh << 5);
    if (part & 1) {
#pragma unroll
      for (int j = 0; j < 2; ++j)
        gload_lds16(srcB[j] + kt, &Bs[buf * BBUF + kh * BKH + dB[j]]);
    } else {
#pragma unroll
      for (int j = 0; j < LA; ++j)
        gload_lds16(srcA[j] + kt, &As[buf * ABUF + kh * AKH + dA[j]]);
    }
  };

  // ---- fragment read offsets (swizzled), within a kh-region ----
  int aoffs[MI], boffs[4];
#pragma unroll
  for (int mi = 0; mi < MI; ++mi) {
    int row = wm * (BM / 2) + mi * 16 + l15;
    aoffs[mi] = row * 32 + ((l4 + (row >> 1)) & 3) * 8;
  }
#pragma unroll
  for (int ni = 0; ni < 4; ++ni) {
    int row = wn * 64 + ni * 16 + l15;
    boffs[ni] = row * 32 + ((l4 + (row >> 1)) & 3) * 8;
  }

  f32x4 acc[MI][4] = {};
  const int nt = K >> 6;
  const int NU = nt << 2;

  // prologue: tile 0 (4 units) + tile 1 parts 0..2
#pragma unroll
  for (int u = 0; u < 7; ++u) if (u < NU) stage_unit(u);
  if constexpr (BM == 256) WAITVM6; else WAITVM4;
  __builtin_amdgcn_s_barrier();
  __builtin_amdgcn_sched_barrier(0);

  for (int t = 0; t < nt; ++t) {
    const int buf = t & 1;
    const ushort_t* Ab = &As[buf * ABUF];
    const ushort_t* Bb = &Bs[buf * BBUF];
    short8 af[MI], bfr[4];

    // ---- phase 0: kh0, ni 0-1 ----
#pragma unroll
    for (int mi = 0; mi < MI; ++mi) af[mi] = *(const short8*)&Ab[aoffs[mi]];
    bfr[0] = *(const short8*)&Bb[boffs[0]];
    bfr[1] = *(const short8*)&Bb[boffs[1]];
    if (7 + 4 * t < NU) stage_unit(7 + 4 * t);
    __builtin_amdgcn_s_barrier();
    __builtin_amdgcn_sched_barrier(0);
    __builtin_amdgcn_s_setprio(1);
#pragma unroll
    for (int mi = 0; mi < MI; ++mi) {
      acc[mi][0] = __builtin_amdgcn_mfma_f32_16x16x32_bf16(af[mi], bfr[0], acc[mi][0], 0, 0, 0);
      acc[mi][1] = __builtin_amdgcn_mfma_f32_16x16x32_bf16(af[mi], bfr[1], acc[mi][1], 0, 0, 0);
    }
    __builtin_amdgcn_s_setprio(0);
    __builtin_amdgcn_s_barrier();
    __builtin_amdgcn_sched_barrier(0);

    // ---- phase 1: kh0, ni 2-3 ----
    bfr[2] = *(const short8*)&Bb[boffs[2]];
    bfr[3] = *(const short8*)&Bb[boffs[3]];
    if (8 + 4 * t < NU) stage_unit(8 + 4 * t);
    __builtin_amdgcn_s_barrier();
    __builtin_amdgcn_sched_barrier(0);
    __builtin_amdgcn_s_setprio(1);
#pragma unroll
    for (int mi = 0; mi < MI; ++mi) {
      acc[mi][2] = __builtin_amdgcn_mfma_f32_16x16x32_bf16(af[mi], bfr[2], acc[mi][2], 0, 0, 0);
      acc[mi][3] = __builtin_amdgcn_mfma_f32_16x16x32_bf16(af[mi], bfr[3], acc[mi][3], 0, 0, 0);
    }
    __builtin_amdgcn_s_setprio(0);
    __builtin_amdgcn_s_barrier();
    __builtin_amdgcn_sched_barrier(0);

    // ---- phase 2: kh1, ni 0-1 ----
#pragma unroll
    for (int mi = 0; mi < MI; ++mi) af[mi] = *(const short8*)&Ab[AKH + aoffs[mi]];
    bfr[0] = *(const short8*)&Bb[BKH + boffs[0]];
    bfr[1] = *(const short8*)&Bb[BKH + boffs[1]];
    if (9 + 4 * t < NU) stage_unit(9 + 4 * t);
    __builtin_amdgcn_s_barrier();
    __builtin_amdgcn_sched_barrier(0);
    __builtin_amdgcn_s_setprio(1);
#pragma unroll
    for (int mi = 0; mi < MI; ++mi) {
      acc[mi][0] = __builtin_amdgcn_mfma_f32_16x16x32_bf16(af[mi], bfr[0], acc[mi][0], 0, 0, 0);
      acc[mi][1] = __builtin_amdgcn_mfma_f32_16x16x32_bf16(af[mi], bfr[1], acc[mi][1], 0, 0, 0);
    }
    __builtin_amdgcn_s_setprio(0);
    __builtin_amdgcn_s_barrier();
    __builtin_amdgcn_sched_barrier(0);

    // ---- phase 3: kh1, ni 2-3 ----
    bfr[2] = *(const short8*)&Bb[BKH + boffs[2]];
    bfr[3] = *(const short8*)&Bb[BKH + boffs[3]];
    if (10 + 4 * t < NU) stage_unit(10 + 4 * t);
    if (t < nt - 2) { if constexpr (BM == 256) WAITVM6; else WAITVM4; }
    else if (t == nt - 2) { WAITVM0; }
    __builtin_amdgcn_s_barrier();
    __builtin_amdgcn_sched_barrier(0);
    __builtin_amdgcn_s_setprio(1);
#pragma unroll
    for (int mi = 0; mi < MI; ++mi) {
      acc[mi][2] = __builtin_amdgcn_mfma_f32_16x16x32_bf16(af[mi], bfr[2], acc[mi][2], 0, 0, 0);
      acc[mi][3] = __builtin_amdgcn_mfma_f32_16x16x32_bf16(af[mi], bfr[3], acc[mi][3], 0, 0, 0);
    }
    __builtin_amdgcn_s_setprio(0);
    __builtin_amdgcn_s_barrier();
    __builtin_amdgcn_sched_barrier(0);
  }

  // ---- epilogue: per-wave LDS transpose -> coalesced 16B stores ----
  float* fl = (float*)&Bs[0] + wave * (16 * 68);
  const long grow0 = bm0 + wm * (BM / 2);
  const long gcol0 = bn0 + wn * 64;
  const int c8 = lane & 7;
  const f32x4 bb0 = *(const f32x4*)&bias[gcol0 + c8 * 8];
  const f32x4 bb1 = *(const f32x4*)&bias[gcol0 + c8 * 8 + 4];

#pragma unroll
  for (int mi = 0; mi < MI; ++mi) {
#pragma unroll
    for (int ni = 0; ni < 4; ++ni)
#pragma unroll
      for (int r = 0; r < 4; ++r)
        fl[(l4 * 4 + r) * 68 + ni * 16 + l15] = acc[mi][ni][r];
#pragma unroll
    for (int pass = 0; pass < 2; ++pass) {
      int row = pass * 8 + (lane >> 3);
      f32x4 v0 = *(const f32x4*)&fl[row * 68 + c8 * 8];
      f32x4 v1 = *(const f32x4*)&fl[row * 68 + c8 * 8 + 4];
      v0 += bb0; v1 += bb1;
      const long grow = grow0 + mi * 16 + row;
      if (MODE == 1) {
#pragma unroll
        for (int e = 0; e < 4; ++e) {
          v0[e] = 0.5f * v0[e] * (1.0f + erff(v0[e] * 0.70710678118f));
          v1[e] = 0.5f * v1[e] * (1.0f + erff(v1[e] * 0.70710678118f));
        }
      }
      if (MODE == 2) {
        float* rp = resid + (size_t)grow * N + gcol0 + c8 * 8;
        f32x4 r0 = *(const f32x4*)rp;
        f32x4 r1 = *(const f32x4*)(rp + 4);
        r0 += v0; r1 += v1;
        *(f32x4*)rp = r0;
        *(f32x4*)(rp + 4) = r1;
      } else {
        short8 o;
#pragma unroll
        for (int e = 0; e < 4; ++e) { o[e] = (short)f2bf(v0[e]); o[e + 4] = (short)f2bf(v1[e]); }
        *(short8*)&outb[(size_t)grow * N + gcol0 + c8 * 8] = o;
      }
    }
  }
}

// ---------------------------------------------------------------------------
// Fused block-causal flash attention over packed QKV [8192][3072] bf16.
// 1D grid 2048: bid = qb*128 + (b*16+h); 4 blocks/CU.
// ---------------------------------------------------------------------------
__global__ __launch_bounds__(256, 4)
void attn_kernel(const ushort_t* __restrict__ qkv, ushort_t* __restrict__ y)
{
  __shared__ __align__(16) ushort_t Qs[64 * 64];
  __shared__ __align__(16) ushort_t Ks[64 * 64];
  __shared__ __align__(16) ushort_t Vts[64 * 64];  // transposed: [d][kv]
  __shared__ __align__(16) ushort_t Ps[64 * 64];
  const int tid = threadIdx.x;
  const int lane = tid & 63, wave = tid >> 6;
  const int l15 = lane & 15, l4 = lane >> 4;
  const int w16 = wave * 16;
  const int bid = blockIdx.x;
  const int pair = bid & 127, qb = bid >> 7;
  const int h = pair & 15, b = pair >> 4;
  const int qoff = h * HD, koff = C + h * HD, voff = 2 * C + h * HD;
  const size_t qrow0 = (size_t)(b * T + qb * 64);

#pragma unroll
  for (int j = 0; j < 2; ++j) {
    int cidx = j * 256 + tid;
    int row = cidx >> 3, cl = (cidx & 7) ^ (row & 7);
    gload_lds16(qkv + (qrow0 + row) * CS + qoff + cl * 8, &Qs[cidx * 8]);
  }

  f32x4 o[4] = {};
  float mrun[4] = {-INFINITY, -INFINITY, -INFINITY, -INFINITY};
  float lrun[4] = {0.f, 0.f, 0.f, 0.f};

  __syncthreads();

  for (int kvb = 0; kvb <= qb; ++kvb) {
    const size_t krow0 = (size_t)(b * T + kvb * 64);
#pragma unroll
    for (int j = 0; j < 2; ++j) {
      int cidx = j * 256 + tid;
      int row = cidx >> 3, cl = (cidx & 7) ^ (row & 7);
      gload_lds16(qkv + (krow0 + row) * CS + koff + cl * 8, &Ks[cidx * 8]);
    }
#pragma unroll
    for (int pass = 0; pass < 2; ++pass) {
      int dc = (tid >> 6) + pass * 4;
      int kvr = tid & 63;
      const ushort_t* src = qkv + (krow0 + kvr) * CS + voff + dc * 8;
      short8 vv = *(const short8*)src;
#pragma unroll
      for (int i = 0; i < 8; ++i) {
        int d = dc * 8 + i;
        Vts[d * 64 + (((kvr >> 3) ^ (d & 7)) << 3) + (kvr & 7)] = (ushort_t)vv[i];
      }
    }
    __syncthreads();

    f32x4 s[4] = {};
#pragma unroll
    for (int ks = 0; ks < 2; ++ks) {
      int arow = w16 + l15;
      int pa = (ks * 4 + l4) ^ (arow & 7);
      short8 aq = *(const short8*)&Qs[arow * 64 + pa * 8];
#pragma unroll
      for (int n = 0; n < 4; ++n) {
        int br = n * 16 + l15;
        int pb = (ks * 4 + l4) ^ (br & 7);
        short8 bk2 = *(const short8*)&Ks[br * 64 + pb * 8];
        s[n] = __builtin_amdgcn_mfma_f32_16x16x32_bf16(aq, bk2, s[n], 0, 0, 0);
      }
    }

#pragma unroll
    for (int r = 0; r < 4; ++r) {
      float mx = fmaxf(fmaxf(s[0][r], s[1][r]), fmaxf(s[2][r], s[3][r]));
#pragma unroll
      for (int d = 1; d < 16; d <<= 1) mx = fmaxf(mx, __shfl_xor(mx, d, 16));
      mx *= 0.125f;
      float mnew = fmaxf(mrun[r], mx);
      float alpha = __expf(mrun[r] - mnew);
      float rowsum = 0.f;
      int qr = w16 + l4 * 4 + r;
#pragma unroll
      for (int n = 0; n < 4; ++n) {
        float pv = __expf(s[n][r] * 0.125f - mnew);
        rowsum += pv;
        int kv = n * 16 + l15;
        Ps[qr * 64 + (((kv >> 3) ^ (qr & 7)) << 3) + (kv & 7)] = f2bf(pv);
      }
#pragma unroll
      for (int d = 1; d < 16; d <<= 1) rowsum += __shfl_xor(rowsum, d, 16);
      mrun[r] = mnew;
      lrun[r] = lrun[r] * alpha + rowsum;
      o[0][r] *= alpha; o[1][r] *= alpha; o[2][r] *= alpha; o[3][r] *= alpha;
    }

#pragma unroll
    for (int ks = 0; ks < 2; ++ks) {
      int arow = w16 + l15;
      int pa = (ks * 4 + l4) ^ (arow & 7);
      short8 ap = *(const short8*)&Ps[arow * 64 + pa * 8];
#pragma unroll
      for (int n = 0; n < 4; ++n) {
        int vr = n * 16 + l15;
        int pb = (ks * 4 + l4) ^ (vr & 7);
        short8 bvv = *(const short8*)&Vts[vr * 64 + pb * 8];
        o[n] = __builtin_amdgcn_mfma_f32_16x16x32_bf16(ap, bvv, o[n], 0, 0, 0);
      }
    }
    __syncthreads();
  }

#pragma unroll
  for (int n = 0; n < 4; ++n) {
#pragma unroll
    for (int r = 0; r < 4; ++r) {
      float val = o[n][r] / lrun[r];
      y[(qrow0 + w16 + l4 * 4 + r) * C + h * HD + n * 16 + l15] = f2bf(val);
    }
  }
}

// ---------------------------------------------------------------------------
// LayerNorm over C=1024. One block (256 thr) per row.
// ---------------------------------------------------------------------------
template<int OUTBF16>
__global__ __launch_bounds__(256, 4)
void ln_kernel(const float* __restrict__ x, const float* __restrict__ w,
               const float* __restrict__ bprm, void* __restrict__ out)
{
  const size_t row = blockIdx.x;
  const int tid = threadIdx.x;
  f32x4 xv = ((const f32x4*)(x + row * 1024))[tid];
  float s1 = xv[0] + xv[1] + xv[2] + xv[3];
  float s2 = xv[0] * xv[0] + xv[1] * xv[1] + xv[2] * xv[2] + xv[3] * xv[3];
#pragma unroll
  for (int m = 1; m < 64; m <<= 1) {
    s1 += __shfl_xor(s1, m);
    s2 += __shfl_xor(s2, m);
  }
  __shared__ float red[8];
  const int wave = tid >> 6, lane = tid & 63;
  if (lane == 0) { red[wave * 2] = s1; red[wave * 2 + 1] = s2; }
  __syncthreads();
  s1 = red[0] + red[2] + red[4] + red[6];
  s2 = red[1] + red[3] + red[5] + red[7];
  const float mean = s1 * (1.f / 1024.f);
  const float var = s2 * (1.f / 1024.f) - mean * mean;
  const float rstd = rsqrtf(var + 1e-5f);
  f32x4 wv = ((const f32x4*)w)[tid];
  f32x4 bv = ((const f32x4*)bprm)[tid];
  f32x4 ov;
#pragma unroll
  for (int c2 = 0; c2 < 4; ++c2) ov[c2] = (xv[c2] - mean) * rstd * wv[c2] + bv[c2];
  if (OUTBF16) {
    ushort4 u;
    u.x = f2bf(ov[0]); u.y = f2bf(ov[1]); u.z = f2bf(ov[2]); u.w = f2bf(ov[3]);
    ((ushort4*)out)[row * 256 + tid] = u;
  } else {
    ((f32x4*)out)[row * 256 + tid] = ov;
  }
}

// ---------------------------------------------------------------------------
extern "C" void kernel_launch(void* const* d_in, const int* in_sizes, int n_in,
                              void* d_out, int out_size, void* d_ws, size_t ws_size,
                              hipStream_t stream)
{
  const float* seq  = (const float*)d_in[0];
  const float* Wq   = (const float*)d_in[2];  const float* bq = (const float*)d_in[3];
  const float* Wk   = (const float*)d_in[4];  const float* bk = (const float*)d_in[5];
  const float* Wv   = (const float*)d_in[6];  const float* bv = (const float*)d_in[7];
  const float* Wo   = (const float*)d_in[8];  const float* bo = (const float*)d_in[9];
  const float* ln1w = (const float*)d_in[10]; const float* ln1b = (const float*)d_in[11];
  const float* ln2w = (const float*)d_in[12]; const float* ln2b = (const float*)d_in[13];
  const float* W1   = (const float*)d_in[14]; const float* b1 = (const float*)d_in[15];
  const float* W2   = (const float*)d_in[16]; const float* b2 = (const float*)d_in[17];
  const float* lnfw = (const float*)d_in[18]; const float* lnfb = (const float*)d_in[19];

  char* ws = (char*)d_ws;
  size_t off = 0;
  float* X = (float*)(ws + off);         off += (size_t)MROWS * C * 4;       // 32MB residual
  ushort_t* Hb = (ushort_t*)(ws + off);  off += (size_t)MROWS * C * 2;       // 16MB ln out
  ushort_t* Yb = (ushort_t*)(ws + off);  off += (size_t)MROWS * C * 2;       // 16MB attn out
  ushort_t* BIG = (ushort_t*)(ws + off); off += (size_t)MROWS * 4 * C * 2;   // 64MB QKV|gelu
  ushort_t* wqkv = (ushort_t*)(ws + off); off += (size_t)3 * C * C * 2;      // 6MB
  ushort_t* wo   = (ushort_t*)(ws + off); off += (size_t)C * C * 2;          // 2MB
  ushort_t* w1   = (ushort_t*)(ws + off); off += (size_t)4 * C * C * 2;      // 8MB
  ushort_t* w2   = (ushort_t*)(ws + off); off += (size_t)4 * C * C * 2;      // 8MB
  float* bqkv = (float*)(ws + off);       off += (size_t)3 * C * 4;          // 12KB
  ushort_t* QKVb = BIG;   // [8192][3072], live qkv-gemm -> attn
  ushort_t* Gb = BIG;     // [8192][4096], live w1 -> w2

  hipMemcpyAsync(X, seq, (size_t)MROWS * C * 4, hipMemcpyDeviceToDevice, stream);

  const dim3 blk(256);
  const dim3 blk512(512);
  const dim3 gQKV(384);     // 32 bm(256) x 12 bn(256)
  const dim3 gWo(256);      // 64 bm(128) x  4 bn(256)
  const dim3 gW1(512);      // 32 bm(256) x 16 bn(256)
  const dim3 gW2(256);      // 64 bm(128) x  4 bn(256)
  const dim3 gAttn(2048);
  const dim3 gConv(6145);

  for (int i = 0; i < NL; ++i) {
    const size_t w1Off = (size_t)i * C * C;
    const size_t w4Off = (size_t)i * 4 * C * C;
    convw_kernel<<<gConv, blk, 0, stream>>>(Wq + w1Off, Wk + w1Off, Wv + w1Off,
                                            Wo + w1Off, W1 + w4Off, W2 + w4Off,
                                            bq + i * C, bk + i * C, bv + i * C,
                                            wqkv, wo, w1, w2, bqkv);
    ln_kernel<1><<<MROWS, blk, 0, stream>>>(X, ln1w + i * C, ln1b + i * C, Hb);
    gemm8p<0, 256><<<gQKV, blk512, 0, stream>>>(Hb, wqkv, bqkv, QKVb, nullptr, C, CS, 12);
    attn_kernel<<<gAttn, blk, 0, stream>>>(QKVb, Yb);
    gemm8p<2, 128><<<gWo, blk512, 0, stream>>>(Yb, wo, bo + i * C, nullptr, X, C, C, 4);
    ln_kernel<1><<<MROWS, blk, 0, stream>>>(X, ln2w + i * C, ln2b + i * C, Hb);
    gemm8p<1, 256><<<gW1, blk512, 0, stream>>>(Hb, w1, b1 + (size_t)i * 4 * C, Gb, nullptr, C, 4 * C, 16);
    gemm8p<2, 128><<<gW2, blk512, 0, stream>>>(Gb, w2, b2 + i * C, nullptr, X, 4 * C, C, 4);
  }
  ln_kernel<0><<<MROWS, blk, 0, stream>>>(X, lnfw, lnfb, (float*)d_out);
}

// Round 6
// 2925.844 us; speedup vs baseline: 1.3129x; 1.0871x over previous
//
#include <hip/hip_runtime.h>
#include <math.h>

typedef unsigned short ushort_t;
typedef __attribute__((ext_vector_type(4))) float f32x4;
typedef __attribute__((ext_vector_type(8))) short short8;

constexpr int BATCH = 8, T = 1024, C = 1024, NH = 16, HD = 64, NL = 8;
constexpr int MROWS = BATCH * T;  // 8192
constexpr int CS = 3 * C;         // packed QKV row stride

#define WAITVM(n) asm volatile("s_waitcnt vmcnt(" #n ")" ::: "memory")
#define WAITLGKM0 asm volatile("s_waitcnt lgkmcnt(0)" ::: "memory")

__device__ __forceinline__ ushort_t f2bf(float f) {
  unsigned u = __builtin_bit_cast(unsigned, f);
  u += 0x7fffu + ((u >> 16) & 1u);
  return (ushort_t)(u >> 16);
}

__device__ __forceinline__ void gload_lds16(const ushort_t* g, ushort_t* l) {
  __builtin_amdgcn_global_load_lds(
      (const __attribute__((address_space(1))) unsigned int*)g,
      (__attribute__((address_space(3))) unsigned int*)l, 16, 0, 0);
}

// ---------------------------------------------------------------------------
// Per-layer weight conversion f32->bf16 + QKV packing (unchanged).
// ---------------------------------------------------------------------------
__global__ __launch_bounds__(256, 8)
void convw_kernel(const float* __restrict__ Wq, const float* __restrict__ Wk,
                  const float* __restrict__ Wv, const float* __restrict__ Wo,
                  const float* __restrict__ W1, const float* __restrict__ W2,
                  const float* __restrict__ bq, const float* __restrict__ bk,
                  const float* __restrict__ bv,
                  ushort_t* __restrict__ wqkv, ushort_t* __restrict__ wo,
                  ushort_t* __restrict__ w1, ushort_t* __restrict__ w2,
                  float* __restrict__ bqkv)
{
  if (blockIdx.x == 6144) {
    int t = threadIdx.x;
    if (t < 384) {
      const float* s = (t < 128) ? (bq + t * 8)
                     : (t < 256) ? (bk + (t - 128) * 8)
                                 : (bv + (t - 256) * 8);
      f32x4 a = ((const f32x4*)s)[0], b = ((const f32x4*)s)[1];
      ((f32x4*)(bqkv + t * 8))[0] = a;
      ((f32x4*)(bqkv + t * 8))[1] = b;
    }
    return;
  }
  int g = blockIdx.x * 256 + threadIdx.x;
  const float* src;
  ushort_t* dst;
  if (g < 393216) {
    int which = g >> 17;
    int r = g & 131071;
    src = (which == 0 ? Wq : which == 1 ? Wk : Wv) + (size_t)r * 8;
    dst = wqkv + (size_t)g * 8;
  } else if (g < 524288) {
    int r = g - 393216;
    src = Wo + (size_t)r * 8; dst = wo + (size_t)r * 8;
  } else if (g < 1048576) {
    int r = g - 524288;
    src = W1 + (size_t)r * 8; dst = w1 + (size_t)r * 8;
  } else {
    int r = g - 1048576;
    src = W2 + (size_t)r * 8; dst = w2 + (size_t)r * 8;
  }
  f32x4 a = ((const f32x4*)src)[0], b = ((const f32x4*)src)[1];
  short8 o;
#pragma unroll
  for (int e = 0; e < 4; ++e) { o[e] = (short)f2bf(a[e]); o[e + 4] = (short)f2bf(b[e]); }
  *(short8*)dst = o;
}

// ---------------------------------------------------------------------------
// m97-style GEMM: out[M,N] = A[M,K](bf16) @ Wb[N,K](bf16)^T + bias
// BM=BN=128, BK=64, 256 thr = 4 waves (2x2), wave tile 64x64, acc[4][4].
// SINGLE 32KB LDS buffer, 2-barrier K-loop (sync; stage; sync; compute) —
// occupancy does the masking: launch_bounds(256,3) -> 3 blocks/CU (m97: 912TF).
// LDS tile [row][8 chunks of 8 bf16], phys chunk = logical ^ (row&7)
// (R2-validated: 0 bank conflicts); linear gload_lds dest + inverse-swizzled
// global source. Epilogue: per-wave LDS transpose -> 16B stores / f32x4 RMW.
// XCD decode: xcd owns 8 contiguous bm panels x all bn (bn-fast).
// MODE 0: bf16 out. MODE 1: exact-erf GELU bf16 out. MODE 2: resid(f32) +=.
// ---------------------------------------------------------------------------
template<int MODE>
__global__ __launch_bounds__(256, 3)
void gemm97(const ushort_t* __restrict__ A, const ushort_t* __restrict__ Wb,
            const float* __restrict__ bias, ushort_t* __restrict__ outb,
            float* __restrict__ resid, int K, int N, int nbn)
{
  __shared__ __align__(16) ushort_t Sm[2 * 128 * 64];  // As | Bs
  ushort_t* As = Sm;
  ushort_t* Bs = Sm + 128 * 64;

  const int tid = threadIdx.x;
  const int lane = tid & 63, wave = tid >> 6;
  const int wm = wave >> 1, wn = wave & 1;
  const int l15 = lane & 15, l4 = lane >> 4;

  const int xcd = blockIdx.x & 7;
  const int local = blockIdx.x >> 3;
  const int bm = xcd * 8 + local / nbn;   // 64 bm panels, 8 per XCD
  const int bn = local % nbn;
  const long bm0 = (long)bm * 128;
  const long bn0 = (long)bn * 128;

  // staging: 1024 chunks of 16B per matrix, 4 per thread each
  const ushort_t* srcA[4]; const ushort_t* srcB[4]; int dst4[4];
#pragma unroll
  for (int j = 0; j < 4; ++j) {
    int cidx = j * 256 + tid;
    int row = cidx >> 3;
    int cl = (cidx & 7) ^ (row & 7);
    srcA[j] = A + (size_t)(bm0 + row) * K + cl * 8;
    srcB[j] = Wb + (size_t)(bn0 + row) * K + cl * 8;
    dst4[j] = cidx * 8;
  }
  // fragment read offsets
  int aoff[2][4], boff[2][4];
#pragma unroll
  for (int ks = 0; ks < 2; ++ks) {
#pragma unroll
    for (int i = 0; i < 4; ++i) {
      int ra = wm * 64 + i * 16 + l15;
      aoff[ks][i] = ra * 64 + (((ks * 4 + l4) ^ (ra & 7)) << 3);
      int rb = wn * 64 + i * 16 + l15;
      boff[ks][i] = rb * 64 + (((ks * 4 + l4) ^ (rb & 7)) << 3);
    }
  }

  f32x4 acc[4][4] = {};
  const int nt = K >> 6;

  for (int t = 0; t < nt; ++t) {
    __syncthreads();                       // prev-tile reads complete (WAR)
    const int kt = t << 6;
#pragma unroll
    for (int j = 0; j < 4; ++j) {
      gload_lds16(srcA[j] + kt, &As[dst4[j]]);
      gload_lds16(srcB[j] + kt, &Bs[dst4[j]]);
    }
    __syncthreads();                       // drains vmcnt: tile resident
#pragma unroll
    for (int ks = 0; ks < 2; ++ks) {
      short8 af[4], bfr[4];
#pragma unroll
      for (int i = 0; i < 4; ++i) {
        af[i] = *(const short8*)&As[aoff[ks][i]];
        bfr[i] = *(const short8*)&Bs[boff[ks][i]];
      }
#pragma unroll
      for (int mi = 0; mi < 4; ++mi)
#pragma unroll
        for (int ni = 0; ni < 4; ++ni)
          acc[mi][ni] = __builtin_amdgcn_mfma_f32_16x16x32_bf16(
              af[mi], bfr[ni], acc[mi][ni], 0, 0, 0);
    }
  }
  __syncthreads();                         // all reads done; reuse LDS

  // ---- epilogue: per-wave LDS transpose -> coalesced stores ----
  float* fl = (float*)Sm + wave * (16 * 68);
  const long grow0 = bm0 + wm * 64;
  const long gcol0 = bn0 + wn * 64;
  const int c8 = lane & 7;
  const f32x4 bb0 = *(const f32x4*)&bias[gcol0 + c8 * 8];
  const f32x4 bb1 = *(const f32x4*)&bias[gcol0 + c8 * 8 + 4];

#pragma unroll
  for (int mi = 0; mi < 4; ++mi) {
#pragma unroll
    for (int ni = 0; ni < 4; ++ni)
#pragma unroll
      for (int r = 0; r < 4; ++r)
        fl[(l4 * 4 + r) * 68 + ni * 16 + l15] = acc[mi][ni][r];
#pragma unroll
    for (int pass = 0; pass < 2; ++pass) {
      int row = pass * 8 + (lane >> 3);
      f32x4 v0 = *(const f32x4*)&fl[row * 68 + c8 * 8];
      f32x4 v1 = *(const f32x4*)&fl[row * 68 + c8 * 8 + 4];
      v0 += bb0; v1 += bb1;
      const long grow = grow0 + mi * 16 + row;
      if (MODE == 1) {
#pragma unroll
        for (int e = 0; e < 4; ++e) {
          v0[e] = 0.5f * v0[e] * (1.0f + erff(v0[e] * 0.70710678118f));
          v1[e] = 0.5f * v1[e] * (1.0f + erff(v1[e] * 0.70710678118f));
        }
      }
      if (MODE == 2) {
        float* rp = resid + (size_t)grow * N + gcol0 + c8 * 8;
        f32x4 r0 = *(const f32x4*)rp;
        f32x4 r1 = *(const f32x4*)(rp + 4);
        r0 += v0; r1 += v1;
        *(f32x4*)rp = r0;
        *(f32x4*)(rp + 4) = r1;
      } else {
        short8 o;
#pragma unroll
        for (int e = 0; e < 4; ++e) { o[e] = (short)f2bf(v0[e]); o[e + 4] = (short)f2bf(v1[e]); }
        *(short8*)&outb[(size_t)grow * N + gcol0 + c8 * 8] = o;
      }
    }
  }
}

// ---------------------------------------------------------------------------
// Fused block-causal flash attention, pipelined.
// Grid 1024: bid -> bh = bid&127, qpair = bid>>7. Block processes q-tiles
// {qpair, 15-qpair} -> uniform 17 kv-tiles/block; exactly one 4-block/CU
// generation. Q in registers; K double-buffered via global_load_lds; V
// prefetched to regs one tile ahead (T14), scattered to dbuf Vts in LDS.
// Raw s_barriers: lgkmcnt(0) before mid barrier (P/Vt visibility),
// counted vmcnt(2) before end barrier (K[t+1] resident; V regs stay in
// flight). No vmcnt(0) drain in the loop.
// ---------------------------------------------------------------------------
__global__ __launch_bounds__(256, 4)
void attn_kernel(const ushort_t* __restrict__ qkv, ushort_t* __restrict__ y)
{
  __shared__ __align__(16) ushort_t Ks[2][64 * 64];
  __shared__ __align__(16) ushort_t Vts[2][64 * 64];  // [d][kv] swizzled
  __shared__ __align__(16) ushort_t Ps[64 * 64];
  const int tid = threadIdx.x;
  const int lane = tid & 63, wave = tid >> 6;
  const int l15 = lane & 15, l4 = lane >> 4;
  const int w16 = wave * 16;
  const int bh = blockIdx.x & 127, qpair = blockIdx.x >> 7;
  const int h = bh & 15, b = bh >> 4;
  const int qoff = h * HD, koff = C + h * HD, voff = 2 * C + h * HD;
  const int kvr = tid & 63, dc = tid >> 6;

#pragma unroll
  for (int half = 0; half < 2; ++half) {
    const int qb = half == 0 ? qpair : 15 - qpair;
    const int nkv = qb + 1;
    const size_t qrow0 = (size_t)(b * T + qb * 64);

    // Q fragments directly to registers
    short8 aq[2];
#pragma unroll
    for (int ks = 0; ks < 2; ++ks)
      aq[ks] = *(const short8*)(qkv + (qrow0 + w16 + l15) * CS + qoff + ks * 32 + l4 * 8);

    f32x4 o[4] = {};
    float mrun[4] = {-INFINITY, -INFINITY, -INFINITY, -INFINITY};
    float lrun[4] = {0.f, 0.f, 0.f, 0.f};

    // ---- prologue: stage K[0], prefetch V[0] to regs ----
    {
      const size_t krow0 = (size_t)(b * T);
#pragma unroll
      for (int j = 0; j < 2; ++j) {
        int cidx = j * 256 + tid;
        int row = cidx >> 3, cl = (cidx & 7) ^ (row & 7);
        gload_lds16(qkv + (krow0 + row) * CS + koff + cl * 8, &Ks[0][cidx * 8]);
      }
    }
    short8 vreg0, vreg1;
    vreg0 = *(const short8*)(qkv + ((size_t)(b * T) + kvr) * CS + voff + dc * 8);
    vreg1 = *(const short8*)(qkv + ((size_t)(b * T) + kvr) * CS + voff + (dc + 4) * 8);
    WAITVM(2);                       // K[0] resident (V regs may be in flight)
    __builtin_amdgcn_s_barrier();

    for (int t = 0; t < nkv; ++t) {
      const int buf = t & 1;
      const bool more = (t + 1 < nkv);
      short8 vnext0, vnext1;
      if (more) {
        const size_t krow1 = (size_t)(b * T + (t + 1) * 64);
#pragma unroll
        for (int j = 0; j < 2; ++j) {
          int cidx = j * 256 + tid;
          int row = cidx >> 3, cl = (cidx & 7) ^ (row & 7);
          gload_lds16(qkv + (krow1 + row) * CS + koff + cl * 8, &Ks[buf ^ 1][cidx * 8]);
        }
        vnext0 = *(const short8*)(qkv + (krow1 + kvr) * CS + voff + dc * 8);
        vnext1 = *(const short8*)(qkv + (krow1 + kvr) * CS + voff + (dc + 4) * 8);
      }

      // ---- S = Q K^T ----
      f32x4 s[4] = {};
#pragma unroll
      for (int ks = 0; ks < 2; ++ks) {
#pragma unroll
        for (int n = 0; n < 4; ++n) {
          int br = n * 16 + l15;
          int pb = (ks * 4 + l4) ^ (br & 7);
          short8 bk2 = *(const short8*)&Ks[buf][br * 64 + pb * 8];
          s[n] = __builtin_amdgcn_mfma_f32_16x16x32_bf16(aq[ks], bk2, s[n], 0, 0, 0);
        }
      }

      // ---- online softmax, P -> LDS ----
#pragma unroll
      for (int r = 0; r < 4; ++r) {
        float mx = fmaxf(fmaxf(s[0][r], s[1][r]), fmaxf(s[2][r], s[3][r]));
#pragma unroll
        for (int d = 1; d < 16; d <<= 1) mx = fmaxf(mx, __shfl_xor(mx, d, 16));
        mx *= 0.125f;
        float mnew = fmaxf(mrun[r], mx);
        float alpha = __expf(mrun[r] - mnew);
        float rowsum = 0.f;
        int qr = w16 + l4 * 4 + r;
#pragma unroll
        for (int n = 0; n < 4; ++n) {
          float pv = __expf(s[n][r] * 0.125f - mnew);
          rowsum += pv;
          int kv = n * 16 + l15;
          Ps[qr * 64 + (((kv >> 3) ^ (qr & 7)) << 3) + (kv & 7)] = f2bf(pv);
        }
#pragma unroll
        for (int d = 1; d < 16; d <<= 1) rowsum += __shfl_xor(rowsum, d, 16);
        mrun[r] = mnew;
        lrun[r] = lrun[r] * alpha + rowsum;
        o[0][r] *= alpha; o[1][r] *= alpha; o[2][r] *= alpha; o[3][r] *= alpha;
      }

      // ---- scatter V[t] regs -> Vts[buf] (swizzled [d][kv]) ----
#pragma unroll
      for (int i = 0; i < 8; ++i) {
        int d0 = dc * 8 + i;
        Vts[buf][d0 * 64 + (((kvr >> 3) ^ (d0 & 7)) << 3) + (kvr & 7)] = (ushort_t)vreg0[i];
        int d1 = (dc + 4) * 8 + i;
        Vts[buf][d1 * 64 + (((kvr >> 3) ^ (d1 & 7)) << 3) + (kvr & 7)] = (ushort_t)vreg1[i];
      }
      vreg0 = vnext0; vreg1 = vnext1;

      WAITLGKM0;                         // P & Vt writes visible
      __builtin_amdgcn_s_barrier();

      // ---- O += P V ----
#pragma unroll
      for (int ks = 0; ks < 2; ++ks) {
        int arow = w16 + l15;
        int pa = (ks * 4 + l4) ^ (arow & 7);
        short8 ap = *(const short8*)&Ps[arow * 64 + pa * 8];
#pragma unroll
        for (int n = 0; n < 4; ++n) {
          int vr = n * 16 + l15;
          int pb = (ks * 4 + l4) ^ (vr & 7);
          short8 bvv = *(const short8*)&Vts[buf][vr * 64 + pb * 8];
          o[n] = __builtin_amdgcn_mfma_f32_16x16x32_bf16(ap, bvv, o[n], 0, 0, 0);
        }
      }

      if (more) { WAITVM(2); }           // K[t+1] resident before barrier
      __builtin_amdgcn_s_barrier();
    }

    // ---- write y ----
#pragma unroll
    for (int n = 0; n < 4; ++n) {
#pragma unroll
      for (int r = 0; r < 4; ++r) {
        float val = o[n][r] / lrun[r];
        y[(qrow0 + w16 + l4 * 4 + r) * C + h * HD + n * 16 + l15] = f2bf(val);
      }
    }
    __builtin_amdgcn_s_barrier();        // quiesce before next half reuses LDS
  }
}

// ---------------------------------------------------------------------------
// LayerNorm over C=1024. One block (256 thr) per row.
// ---------------------------------------------------------------------------
template<int OUTBF16>
__global__ __launch_bounds__(256, 4)
void ln_kernel(const float* __restrict__ x, const float* __restrict__ w,
               const float* __restrict__ bprm, void* __restrict__ out)
{
  const size_t row = blockIdx.x;
  const int tid = threadIdx.x;
  f32x4 xv = ((const f32x4*)(x + row * 1024))[tid];
  float s1 = xv[0] + xv[1] + xv[2] + xv[3];
  float s2 = xv[0] * xv[0] + xv[1] * xv[1] + xv[2] * xv[2] + xv[3] * xv[3];
#pragma unroll
  for (int m = 1; m < 64; m <<= 1) {
    s1 += __shfl_xor(s1, m);
    s2 += __shfl_xor(s2, m);
  }
  __shared__ float red[8];
  const int wave = tid >> 6, lane = tid & 63;
  if (lane == 0) { red[wave * 2] = s1; red[wave * 2 + 1] = s2; }
  __syncthreads();
  s1 = red[0] + red[2] + red[4] + red[6];
  s2 = red[1] + red[3] + red[5] + red[7];
  const float mean = s1 * (1.f / 1024.f);
  const float var = s2 * (1.f / 1024.f) - mean * mean;
  const float rstd = rsqrtf(var + 1e-5f);
  f32x4 wv = ((const f32x4*)w)[tid];
  f32x4 bv = ((const f32x4*)bprm)[tid];
  f32x4 ov;
#pragma unroll
  for (int c2 = 0; c2 < 4; ++c2) ov[c2] = (xv[c2] - mean) * rstd * wv[c2] + bv[c2];
  if (OUTBF16) {
    ushort4 u;
    u.x = f2bf(ov[0]); u.y = f2bf(ov[1]); u.z = f2bf(ov[2]); u.w = f2bf(ov[3]);
    ((ushort4*)out)[row * 256 + tid] = u;
  } else {
    ((f32x4*)out)[row * 256 + tid] = ov;
  }
}

// ---------------------------------------------------------------------------
extern "C" void kernel_launch(void* const* d_in, const int* in_sizes, int n_in,
                              void* d_out, int out_size, void* d_ws, size_t ws_size,
                              hipStream_t stream)
{
  const float* seq  = (const float*)d_in[0];
  const float* Wq   = (const float*)d_in[2];  const float* bq = (const float*)d_in[3];
  const float* Wk   = (const float*)d_in[4];  const float* bk = (const float*)d_in[5];
  const float* Wv   = (const float*)d_in[6];  const float* bv = (const float*)d_in[7];
  const float* Wo   = (const float*)d_in[8];  const float* bo = (const float*)d_in[9];
  const float* ln1w = (const float*)d_in[10]; const float* ln1b = (const float*)d_in[11];
  const float* ln2w = (const float*)d_in[12]; const float* ln2b = (const float*)d_in[13];
  const float* W1   = (const float*)d_in[14]; const float* b1 = (const float*)d_in[15];
  const float* W2   = (const float*)d_in[16]; const float* b2 = (const float*)d_in[17];
  const float* lnfw = (const float*)d_in[18]; const float* lnfb = (const float*)d_in[19];

  char* ws = (char*)d_ws;
  size_t off = 0;
  float* X = (float*)(ws + off);         off += (size_t)MROWS * C * 4;       // 32MB residual
  ushort_t* Hb = (ushort_t*)(ws + off);  off += (size_t)MROWS * C * 2;       // 16MB ln out
  ushort_t* Yb = (ushort_t*)(ws + off);  off += (size_t)MROWS * C * 2;       // 16MB attn out
  ushort_t* BIG = (ushort_t*)(ws + off); off += (size_t)MROWS * 4 * C * 2;   // 64MB QKV|gelu
  ushort_t* wqkv = (ushort_t*)(ws + off); off += (size_t)3 * C * C * 2;      // 6MB
  ushort_t* wo   = (ushort_t*)(ws + off); off += (size_t)C * C * 2;          // 2MB
  ushort_t* w1   = (ushort_t*)(ws + off); off += (size_t)4 * C * C * 2;      // 8MB
  ushort_t* w2   = (ushort_t*)(ws + off); off += (size_t)4 * C * C * 2;      // 8MB
  float* bqkv = (float*)(ws + off);       off += (size_t)3 * C * 4;          // 12KB
  ushort_t* QKVb = BIG;   // [8192][3072], live qkv-gemm -> attn
  ushort_t* Gb = BIG;     // [8192][4096], live w1 -> w2

  hipMemcpyAsync(X, seq, (size_t)MROWS * C * 4, hipMemcpyDeviceToDevice, stream);

  const dim3 blk(256);
  const dim3 gQKV(1536);    // 64 bm x 24 bn
  const dim3 gWo(512);      // 64 bm x  8 bn
  const dim3 gW1(2048);     // 64 bm x 32 bn
  const dim3 gW2(512);      // 64 bm x  8 bn
  const dim3 gAttn(1024);
  const dim3 gConv(6145);

  for (int i = 0; i < NL; ++i) {
    const size_t w1Off = (size_t)i * C * C;
    const size_t w4Off = (size_t)i * 4 * C * C;
    convw_kernel<<<gConv, blk, 0, stream>>>(Wq + w1Off, Wk + w1Off, Wv + w1Off,
                                            Wo + w1Off, W1 + w4Off, W2 + w4Off,
                                            bq + i * C, bk + i * C, bv + i * C,
                                            wqkv, wo, w1, w2, bqkv);
    ln_kernel<1><<<MROWS, blk, 0, stream>>>(X, ln1w + i * C, ln1b + i * C, Hb);
    gemm97<0><<<gQKV, blk, 0, stream>>>(Hb, wqkv, bqkv, QKVb, nullptr, C, CS, 24);
    attn_kernel<<<gAttn, blk, 0, stream>>>(QKVb, Yb);
    gemm97<2><<<gWo, blk, 0, stream>>>(Yb, wo, bo + i * C, nullptr, X, C, C, 8);
    ln_kernel<1><<<MROWS, blk, 0, stream>>>(X, ln2w + i * C, ln2b + i * C, Hb);
    gemm97<1><<<gW1, blk, 0, stream>>>(Hb, w1, b1 + (size_t)i * 4 * C, Gb, nullptr, C, 4 * C, 32);
    gemm97<2><<<gW2, blk, 0, stream>>>(Gb, w2, b2 + i * C, nullptr, X, 4 * C, C, 8);
  }
  ln_kernel<0><<<MROWS, blk, 0, stream>>>(X, lnfw, lnfb, (float*)d_out);
}